// Round 1
// 1083.261 us; speedup vs baseline: 1.8747x; 1.8747x over previous
//
#include <hip/hip_runtime.h>
#include <math.h>

#define HID 1024
#define NH 16
#define HD 64
#define NB 8
#define SEQ 1024
#define MTOK (NB * SEQ)   // 8192 token rows

// bf16 MFMA rewrite: all GEMM-shaped stages on the matrix pipe.
// LDS layout everywhere: [rows][64] bf16, 16B slots XOR-swizzled: slot' = slot ^ (row&7)
// -> ds_read_b128 fragment reads are <=2-way bank conflicts (free), staging writes conflict-free.

typedef __bf16 bf16x8 __attribute__((ext_vector_type(8)));
typedef float f32x4 __attribute__((ext_vector_type(4)));
typedef unsigned short u16x8 __attribute__((ext_vector_type(8)));
typedef unsigned short u16x4 __attribute__((ext_vector_type(4)));

__device__ inline ushort f2bf(float f) {  // RNE f32 -> bf16
  union { float f; unsigned u; } v; v.f = f;
  unsigned r = v.u + 0x7fffu + ((v.u >> 16) & 1u);
  return (ushort)(r >> 16);
}

// ---------------------------------------------------------------------------
// f32 -> bf16 bulk convert; grid covers exactly n/8 threads
// ---------------------------------------------------------------------------
__global__ __launch_bounds__(256) void cvtbf_k(const float* __restrict__ in,
                                               ushort* __restrict__ out) {
  const size_t i = ((size_t)blockIdx.x * 256 + threadIdx.x) * 8;
  const float4 a = *(const float4*)(in + i);
  const float4 b = *(const float4*)(in + i + 4);
  u16x8 r;
  r[0] = f2bf(a.x); r[1] = f2bf(a.y); r[2] = f2bf(a.z); r[3] = f2bf(a.w);
  r[4] = f2bf(b.x); r[5] = f2bf(b.y); r[6] = f2bf(b.z); r[7] = f2bf(b.w);
  *(u16x8*)(out + i) = r;
}

// ---------------------------------------------------------------------------
// C[M,N] = A[M,K]bf16 * W[N,K]bf16^T + bias(f32)
// OUT_MODE 0: f32 row-major [M,N]
// OUT_MODE 1: bf16 head-split [B,H,S,HD]
// OUT_MODE 2: bf16 head-split transposed [B,H,HD,S]   (for v -> ctx B-operand)
// 128x128 tile, 256 thr = 4 waves (2x2), wave tile 64x64 = 4x4 frags of 16x16x32.
// ---------------------------------------------------------------------------
template <int OUT_MODE>
__global__ __launch_bounds__(256) void gemm_bf16_k(
    const ushort* __restrict__ A, const ushort* __restrict__ W,
    const float* __restrict__ bias, float* __restrict__ Cf,
    ushort* __restrict__ Cb, int N, int K) {
  __shared__ ushort As[128 * 64];
  __shared__ ushort Bs[128 * 64];
  const int tid = threadIdx.x;
  const int lane = tid & 63, wave = tid >> 6;
  const int row0 = blockIdx.y * 128, col0 = blockIdx.x * 128;
  const ushort* Ap = A + (size_t)row0 * K;
  const ushort* Wp = W + (size_t)col0 * K;

  // staging map: iter j: row = j*32 + (tid>>3), 16B slot = tid&7 (8 thr cover a 128B row)
  const int srow = tid >> 3, sslot = tid & 7;
  const int swz = sslot ^ (srow & 7);

  u16x8 ra[4], rw[4];
#pragma unroll
  for (int j = 0; j < 4; ++j) {
    ra[j] = *(const u16x8*)(Ap + (size_t)(j * 32 + srow) * K + sslot * 8);
    rw[j] = *(const u16x8*)(Wp + (size_t)(j * 32 + srow) * K + sslot * 8);
  }

  f32x4 acc[4][4];
#pragma unroll
  for (int i = 0; i < 4; ++i)
#pragma unroll
    for (int j = 0; j < 4; ++j)
#pragma unroll
      for (int e = 0; e < 4; ++e) acc[i][j][e] = 0.f;

  const int wm = wave >> 1, wn = wave & 1;
  const int rbase = wm * 64, cbase = wn * 64;
  const int fr = lane & 15, fk = lane >> 4;

  for (int kt = 0; kt < K; kt += 64) {
    __syncthreads();
#pragma unroll
    for (int j = 0; j < 4; ++j) {
      *(u16x8*)(&As[(j * 32 + srow) * 64 + swz * 8]) = ra[j];
      *(u16x8*)(&Bs[(j * 32 + srow) * 64 + swz * 8]) = rw[j];
    }
    __syncthreads();
    if (kt + 64 < K) {  // prefetch next tile; latency hides under MFMA below
#pragma unroll
      for (int j = 0; j < 4; ++j) {
        ra[j] = *(const u16x8*)(Ap + (size_t)(j * 32 + srow) * K + (kt + 64) + sslot * 8);
        rw[j] = *(const u16x8*)(Wp + (size_t)(j * 32 + srow) * K + (kt + 64) + sslot * 8);
      }
    }
#pragma unroll
    for (int kk = 0; kk < 2; ++kk) {
      bf16x8 af[4], bf[4];
#pragma unroll
      for (int f = 0; f < 4; ++f) {
        const int Ra = rbase + f * 16 + fr;
        af[f] = *(const bf16x8*)(&As[Ra * 64 + ((kk * 4 + fk) ^ (Ra & 7)) * 8]);
        const int Rb = cbase + f * 16 + fr;
        bf[f] = *(const bf16x8*)(&Bs[Rb * 64 + ((kk * 4 + fk) ^ (Rb & 7)) * 8]);
      }
#pragma unroll
      for (int i = 0; i < 4; ++i)
#pragma unroll
        for (int j = 0; j < 4; ++j)
          acc[i][j] = __builtin_amdgcn_mfma_f32_16x16x32_bf16(af[i], bf[j], acc[i][j], 0, 0, 0);
    }
  }

  float bv[4];
#pragma unroll
  for (int j = 0; j < 4; ++j) bv[j] = bias[col0 + cbase + j * 16 + fr];

  // C/D map: col = lane&15, row = (lane>>4)*4 + reg  [guide m89]
#pragma unroll
  for (int i = 0; i < 4; ++i) {
#pragma unroll
    for (int e = 0; e < 4; ++e) {
      const int m = row0 + rbase + i * 16 + fk * 4 + e;
#pragma unroll
      for (int j = 0; j < 4; ++j) {
        const int c = col0 + cbase + j * 16 + fr;
        const float val = acc[i][j][e] + bv[j];
        if (OUT_MODE == 0) {
          Cf[(size_t)m * N + c] = val;
        } else {
          const int b_ = m >> 10, s_ = m & 1023;
          const int h_ = c >> 6, hd = c & 63;
          if (OUT_MODE == 1)
            Cb[((size_t)(b_ * NH + h_) << 16) + s_ * 64 + hd] = f2bf(val);
          else
            Cb[((size_t)(b_ * NH + h_) << 16) + hd * 1024 + s_] = f2bf(val);
        }
      }
    }
  }
}

// ---------------------------------------------------------------------------
// scores[bh] = q[bh] (1024x64 bf16) * k[bh]^T * 0.125 -> attn slab (f32)
// ---------------------------------------------------------------------------
__global__ __launch_bounds__(256) void scores_bf16_k(
    const ushort* __restrict__ q, const ushort* __restrict__ kmat,
    float* __restrict__ attn) {
  __shared__ ushort Qs[128 * 64];
  __shared__ ushort Ks[128 * 64];
  const int tid = threadIdx.x;
  const int lane = tid & 63, wave = tid >> 6;
  const int bh = blockIdx.z;
  const int row0 = blockIdx.y * 128, col0 = blockIdx.x * 128;
  const ushort* qp = q + ((size_t)bh << 16) + (size_t)row0 * 64;
  const ushort* kp = kmat + ((size_t)bh << 16) + (size_t)col0 * 64;
  const int srow = tid >> 3, sslot = tid & 7;
  const int swz = sslot ^ (srow & 7);
#pragma unroll
  for (int j = 0; j < 4; ++j) {
    *(u16x8*)(&Qs[(j * 32 + srow) * 64 + swz * 8]) =
        *(const u16x8*)(qp + (size_t)(j * 32 + srow) * 64 + sslot * 8);
    *(u16x8*)(&Ks[(j * 32 + srow) * 64 + swz * 8]) =
        *(const u16x8*)(kp + (size_t)(j * 32 + srow) * 64 + sslot * 8);
  }

  f32x4 acc[4][4];
#pragma unroll
  for (int i = 0; i < 4; ++i)
#pragma unroll
    for (int j = 0; j < 4; ++j)
#pragma unroll
      for (int e = 0; e < 4; ++e) acc[i][j][e] = 0.f;

  const int wm = wave >> 1, wn = wave & 1;
  const int fr = lane & 15, fk = lane >> 4;
  __syncthreads();
#pragma unroll
  for (int kk = 0; kk < 2; ++kk) {
    bf16x8 af[4], bf[4];
#pragma unroll
    for (int f = 0; f < 4; ++f) {
      const int Ra = wm * 64 + f * 16 + fr;
      af[f] = *(const bf16x8*)(&Qs[Ra * 64 + ((kk * 4 + fk) ^ (Ra & 7)) * 8]);
      const int Rb = wn * 64 + f * 16 + fr;
      bf[f] = *(const bf16x8*)(&Ks[Rb * 64 + ((kk * 4 + fk) ^ (Rb & 7)) * 8]);
    }
#pragma unroll
    for (int i = 0; i < 4; ++i)
#pragma unroll
      for (int j = 0; j < 4; ++j)
        acc[i][j] = __builtin_amdgcn_mfma_f32_16x16x32_bf16(af[i], bf[j], acc[i][j], 0, 0, 0);
  }

  float* op = attn + (size_t)bh * SEQ * SEQ;
#pragma unroll
  for (int i = 0; i < 4; ++i)
#pragma unroll
    for (int e = 0; e < 4; ++e) {
      const int m = row0 + wm * 64 + i * 16 + fk * 4 + e;
#pragma unroll
      for (int j = 0; j < 4; ++j) {
        const int n = col0 + wn * 64 + j * 16 + fr;
        op[(size_t)m * SEQ + n] = acc[i][j][e] * 0.125f;
      }
    }
}

// ---------------------------------------------------------------------------
// In-place row softmax over last dim (1024). One 256-thread block per row.
// (unchanged from verified fp32 version; ~BW-bound)
// ---------------------------------------------------------------------------
__global__ __launch_bounds__(256) void softmax_k(float* __restrict__ attn) {
  __shared__ float smax[4], ssum[4];
  float* p = attn + (size_t)blockIdx.x * SEQ;
  const int tid = threadIdx.x;
  const int lane = tid & 63, wid = tid >> 6;
  float4 v = *(const float4*)(p + tid * 4);

  float m4 = fmaxf(fmaxf(v.x, v.y), fmaxf(v.z, v.w));
#pragma unroll
  for (int o = 32; o > 0; o >>= 1) m4 = fmaxf(m4, __shfl_down(m4, o));
  if (lane == 0) smax[wid] = m4;
  __syncthreads();
  const float rmax = fmaxf(fmaxf(smax[0], smax[1]), fmaxf(smax[2], smax[3]));

  v.x = __expf(v.x - rmax);
  v.y = __expf(v.y - rmax);
  v.z = __expf(v.z - rmax);
  v.w = __expf(v.w - rmax);
  float s4 = v.x + v.y + v.z + v.w;
#pragma unroll
  for (int o = 32; o > 0; o >>= 1) s4 += __shfl_down(s4, o);
  if (lane == 0) ssum[wid] = s4;
  __syncthreads();
  const float rs = 1.f / (ssum[0] + ssum[1] + ssum[2] + ssum[3]);

  v.x *= rs; v.y *= rs; v.z *= rs; v.w *= rs;
  *(float4*)(p + tid * 4) = v;
}

// ---------------------------------------------------------------------------
// ctx: per (b,h): attn[bh] (1024x1024 f32, converted to bf16 during staging)
//      * vT[bh] (64x1024 bf16, d-major) -> ctx bf16 [M,HID]
// 128x64 tile, 4 waves (2x2), wave tile 64x32 = 4x2 frags.
// ---------------------------------------------------------------------------
__global__ __launch_bounds__(256) void ctx_bf16_k(
    const float* __restrict__ attn, const ushort* __restrict__ vt,
    ushort* __restrict__ ctxb) {
  __shared__ ushort Ps[128 * 64];
  __shared__ ushort Vs[64 * 64];
  const int tid = threadIdx.x;
  const int lane = tid & 63, wave = tid >> 6;
  const int bh = blockIdx.z;
  const int row0 = blockIdx.y * 128;
  const float* ap = attn + (size_t)bh * SEQ * SEQ + (size_t)row0 * SEQ;
  const ushort* vp = vt + ((size_t)bh << 16);

  // attn staging: iter j: row = j*16 + (tid>>4); float4 pos = tid&15 (16 thr/row, 256B)
  const int ar = tid >> 4, af4 = tid & 15;
  const int awoff = (((af4 >> 1) ^ (ar & 7)) * 8) + (af4 & 1) * 4;  // + row*64 (ushort)
  // vT staging: iter j: row = j*32 + (tid>>3), slot tid&7
  const int srow = tid >> 3, sslot = tid & 7;
  const int swz = sslot ^ (srow & 7);

  float4 pa[8];
  u16x8 rb[2];
#pragma unroll
  for (int j = 0; j < 8; ++j)
    pa[j] = *(const float4*)(ap + (size_t)(j * 16 + ar) * SEQ + af4 * 4);
#pragma unroll
  for (int j = 0; j < 2; ++j)
    rb[j] = *(const u16x8*)(vp + (size_t)(j * 32 + srow) * 1024 + sslot * 8);

  f32x4 acc[4][2];
#pragma unroll
  for (int i = 0; i < 4; ++i)
#pragma unroll
    for (int j = 0; j < 2; ++j)
#pragma unroll
      for (int e = 0; e < 4; ++e) acc[i][j][e] = 0.f;

  const int wm = wave >> 1, wn = wave & 1;
  const int fr = lane & 15, fk = lane >> 4;

  for (int kt = 0; kt < SEQ; kt += 64) {
    __syncthreads();
#pragma unroll
    for (int j = 0; j < 8; ++j) {
      u16x4 w;
      w[0] = f2bf(pa[j].x); w[1] = f2bf(pa[j].y);
      w[2] = f2bf(pa[j].z); w[3] = f2bf(pa[j].w);
      *(u16x4*)(&Ps[(j * 16 + ar) * 64 + awoff]) = w;
    }
#pragma unroll
    for (int j = 0; j < 2; ++j)
      *(u16x8*)(&Vs[(j * 32 + srow) * 64 + swz * 8]) = rb[j];
    __syncthreads();
    if (kt + 64 < SEQ) {
#pragma unroll
      for (int j = 0; j < 8; ++j)
        pa[j] = *(const float4*)(ap + (size_t)(j * 16 + ar) * SEQ + (kt + 64) + af4 * 4);
#pragma unroll
      for (int j = 0; j < 2; ++j)
        rb[j] = *(const u16x8*)(vp + (size_t)(j * 32 + srow) * 1024 + (kt + 64) + sslot * 8);
    }
#pragma unroll
    for (int kk = 0; kk < 2; ++kk) {
      bf16x8 af[4], bf[2];
#pragma unroll
      for (int f = 0; f < 4; ++f) {
        const int R = wm * 64 + f * 16 + fr;
        af[f] = *(const bf16x8*)(&Ps[R * 64 + ((kk * 4 + fk) ^ (R & 7)) * 8]);
      }
#pragma unroll
      for (int f = 0; f < 2; ++f) {
        const int R = wn * 32 + f * 16 + fr;
        bf[f] = *(const bf16x8*)(&Vs[R * 64 + ((kk * 4 + fk) ^ (R & 7)) * 8]);
      }
#pragma unroll
      for (int i = 0; i < 4; ++i)
#pragma unroll
        for (int j = 0; j < 2; ++j)
          acc[i][j] = __builtin_amdgcn_mfma_f32_16x16x32_bf16(af[i], bf[j], acc[i][j], 0, 0, 0);
    }
  }

  const int b_ = bh >> 4, h_ = bh & 15;
#pragma unroll
  for (int i = 0; i < 4; ++i)
#pragma unroll
    for (int e = 0; e < 4; ++e) {
      const int m = row0 + wm * 64 + i * 16 + fk * 4 + e;
#pragma unroll
      for (int j = 0; j < 2; ++j) {
        const int d = wn * 32 + j * 16 + fr;
        ctxb[(size_t)(b_ * SEQ + m) * HID + h_ * HD + d] = f2bf(acc[i][j][e]);
      }
    }
}

// ---------------------------------------------------------------------------
extern "C" void kernel_launch(void* const* d_in, const int* in_sizes, int n_in,
                              void* d_out, int out_size, void* d_ws, size_t ws_size,
                              hipStream_t stream) {
  const float* x  = (const float*)d_in[0];
  const float* Wq = (const float*)d_in[1];
  const float* bq = (const float*)d_in[2];
  const float* Wk = (const float*)d_in[3];
  const float* bk = (const float*)d_in[4];
  const float* Wv = (const float*)d_in[5];
  const float* bv = (const float*)d_in[6];
  const float* Wo = (const float*)d_in[7];
  const float* bo = (const float*)d_in[8];

  float* out  = (float*)d_out;                         // [8,1024,1024]
  float* attn = out + (size_t)MTOK * HID;              // [8,16,1024,1024] f32

  // workspace (bf16/ushort), total 88 MB (< 96 MB used by the prior version)
  ushort* wsb = (ushort*)d_ws;
  ushort* xbf = wsb;                                   // [M,K]       8M
  ushort* wqb = xbf + (size_t)MTOK * HID;              // [N,K]       1M
  ushort* wkb = wqb + HID * HID;
  ushort* wvb = wkb + HID * HID;
  ushort* wob = wvb + HID * HID;
  ushort* qbf = wob + HID * HID;                       // [B,H,S,HD]  8M
  ushort* kbf = qbf + (size_t)MTOK * HID;              // [B,H,S,HD]  8M
  ushort* vtb = kbf + (size_t)MTOK * HID;              // [B,H,HD,S]  8M
  ushort* cxb = vtb + (size_t)MTOK * HID;              // [M,HID]     8M

  const dim3 blk(256);
  cvtbf_k<<<(MTOK * HID) / 2048, blk, 0, stream>>>(x, xbf);
  cvtbf_k<<<(HID * HID) / 2048, blk, 0, stream>>>(Wq, wqb);
  cvtbf_k<<<(HID * HID) / 2048, blk, 0, stream>>>(Wk, wkb);
  cvtbf_k<<<(HID * HID) / 2048, blk, 0, stream>>>(Wv, wvb);
  cvtbf_k<<<(HID * HID) / 2048, blk, 0, stream>>>(Wo, wob);

  const dim3 g1(HID / 128, MTOK / 128);                // (8, 64)
  gemm_bf16_k<1><<<g1, blk, 0, stream>>>(xbf, wqb, bq, nullptr, qbf, HID, HID);
  gemm_bf16_k<1><<<g1, blk, 0, stream>>>(xbf, wkb, bk, nullptr, kbf, HID, HID);
  gemm_bf16_k<2><<<g1, blk, 0, stream>>>(xbf, wvb, bv, nullptr, vtb, HID, HID);

  const dim3 g2(SEQ / 128, SEQ / 128, NB * NH);        // (8, 8, 128)
  scores_bf16_k<<<g2, blk, 0, stream>>>(qbf, kbf, attn);

  softmax_k<<<dim3(NB * NH * SEQ), blk, 0, stream>>>(attn);

  const dim3 g4(1, SEQ / 128, NB * NH);                // (1, 8, 128)
  ctx_bf16_k<<<g4, blk, 0, stream>>>(attn, vtb, cxb);

  gemm_bf16_k<0><<<g1, blk, 0, stream>>>(cxb, wob, bo, out, nullptr, HID, HID);
}

// Round 2
// 839.422 us; speedup vs baseline: 2.4193x; 1.2905x over previous
//
#include <hip/hip_runtime.h>
#include <math.h>

#define HID 1024
#define NH 16
#define HD 64
#define NB 8
#define SEQ 1024
#define MTOK (NB * SEQ)   // 8192 token rows

typedef __bf16 bf16x8 __attribute__((ext_vector_type(8)));
typedef float f32x4 __attribute__((ext_vector_type(4)));
typedef unsigned short u16x8 __attribute__((ext_vector_type(8)));

__device__ inline ushort f2bf(float f) {  // RNE f32 -> bf16
  union { float f; unsigned u; } v; v.f = f;
  unsigned r = v.u + 0x7fffu + ((v.u >> 16) & 1u);
  return (ushort)(r >> 16);
}

// ---------------------------------------------------------------------------
// f32 -> bf16 bulk convert; grid covers exactly n/8 threads
// ---------------------------------------------------------------------------
__global__ __launch_bounds__(256) void cvtbf_k(const float* __restrict__ in,
                                               ushort* __restrict__ out) {
  const size_t i = ((size_t)blockIdx.x * 256 + threadIdx.x) * 8;
  const float4 a = *(const float4*)(in + i);
  const float4 b = *(const float4*)(in + i + 4);
  u16x8 r;
  r[0] = f2bf(a.x); r[1] = f2bf(a.y); r[2] = f2bf(a.z); r[3] = f2bf(a.w);
  r[4] = f2bf(b.x); r[5] = f2bf(b.y); r[6] = f2bf(b.z); r[7] = f2bf(b.w);
  *(u16x8*)(out + i) = r;
}

// ---------------------------------------------------------------------------
// C[M,N] = A[M,K]bf16 * W[N,K]bf16^T + bias(f32)
// OUT_MODE 0: f32 row-major [M,N]
// OUT_MODE 1: bf16 head-split [B,H,S,HD]
// OUT_MODE 2: bf16 head-split transposed [B,H,HD,S]   (for v -> PV B-operand)
// ---------------------------------------------------------------------------
template <int OUT_MODE>
__global__ __launch_bounds__(256) void gemm_bf16_k(
    const ushort* __restrict__ A, const ushort* __restrict__ W,
    const float* __restrict__ bias, float* __restrict__ Cf,
    ushort* __restrict__ Cb, int N, int K) {
  __shared__ ushort As[128 * 64];
  __shared__ ushort Bs[128 * 64];
  const int tid = threadIdx.x;
  const int lane = tid & 63, wave = tid >> 6;
  const int row0 = blockIdx.y * 128, col0 = blockIdx.x * 128;
  const ushort* Ap = A + (size_t)row0 * K;
  const ushort* Wp = W + (size_t)col0 * K;

  const int srow = tid >> 3, sslot = tid & 7;
  const int swz = sslot ^ (srow & 7);

  u16x8 ra[4], rw[4];
#pragma unroll
  for (int j = 0; j < 4; ++j) {
    ra[j] = *(const u16x8*)(Ap + (size_t)(j * 32 + srow) * K + sslot * 8);
    rw[j] = *(const u16x8*)(Wp + (size_t)(j * 32 + srow) * K + sslot * 8);
  }

  f32x4 acc[4][4];
#pragma unroll
  for (int i = 0; i < 4; ++i)
#pragma unroll
    for (int j = 0; j < 4; ++j)
#pragma unroll
      for (int e = 0; e < 4; ++e) acc[i][j][e] = 0.f;

  const int wm = wave >> 1, wn = wave & 1;
  const int rbase = wm * 64, cbase = wn * 64;
  const int fr = lane & 15, fk = lane >> 4;

  for (int kt = 0; kt < K; kt += 64) {
    __syncthreads();
#pragma unroll
    for (int j = 0; j < 4; ++j) {
      *(u16x8*)(&As[(j * 32 + srow) * 64 + swz * 8]) = ra[j];
      *(u16x8*)(&Bs[(j * 32 + srow) * 64 + swz * 8]) = rw[j];
    }
    __syncthreads();
    if (kt + 64 < K) {
#pragma unroll
      for (int j = 0; j < 4; ++j) {
        ra[j] = *(const u16x8*)(Ap + (size_t)(j * 32 + srow) * K + (kt + 64) + sslot * 8);
        rw[j] = *(const u16x8*)(Wp + (size_t)(j * 32 + srow) * K + (kt + 64) + sslot * 8);
      }
    }
#pragma unroll
    for (int kk = 0; kk < 2; ++kk) {
      bf16x8 af[4], bf[4];
#pragma unroll
      for (int f = 0; f < 4; ++f) {
        const int Ra = rbase + f * 16 + fr;
        af[f] = *(const bf16x8*)(&As[Ra * 64 + ((kk * 4 + fk) ^ (Ra & 7)) * 8]);
        const int Rb = cbase + f * 16 + fr;
        bf[f] = *(const bf16x8*)(&Bs[Rb * 64 + ((kk * 4 + fk) ^ (Rb & 7)) * 8]);
      }
#pragma unroll
      for (int i = 0; i < 4; ++i)
#pragma unroll
        for (int j = 0; j < 4; ++j)
          acc[i][j] = __builtin_amdgcn_mfma_f32_16x16x32_bf16(af[i], bf[j], acc[i][j], 0, 0, 0);
    }
  }

  float bv[4];
#pragma unroll
  for (int j = 0; j < 4; ++j) bv[j] = bias[col0 + cbase + j * 16 + fr];

#pragma unroll
  for (int i = 0; i < 4; ++i) {
#pragma unroll
    for (int e = 0; e < 4; ++e) {
      const int m = row0 + rbase + i * 16 + fk * 4 + e;
#pragma unroll
      for (int j = 0; j < 4; ++j) {
        const int c = col0 + cbase + j * 16 + fr;
        const float val = acc[i][j][e] + bv[j];
        if (OUT_MODE == 0) {
          Cf[(size_t)m * N + c] = val;
        } else {
          const int b_ = m >> 10, s_ = m & 1023;
          const int h_ = c >> 6, hd = c & 63;
          if (OUT_MODE == 1)
            Cb[((size_t)(b_ * NH + h_) << 16) + s_ * 64 + hd] = f2bf(val);
          else
            Cb[((size_t)(b_ * NH + h_) << 16) + hd * 1024 + s_] = f2bf(val);
        }
      }
    }
  }
}

// ---------------------------------------------------------------------------
// Fused scores+softmax+PV. One block = 128 q-rows of one (b,h).
// Pass 1: S = QK^T tile-by-tile (MFMA), online row max m + sum l (S discarded).
// Pass 2: recompute S, P = exp((s-m)/8)/l, write f32 attn slab (only slab
//         traffic), P->bf16->LDS (swizzled), PV MFMA accumulate, write ctx.
// 4 waves: wave w owns q-rows w*32..w*32+31. LDS 80KB -> 2 blocks/CU.
// LDS maps (16B-slot XOR swizzles, write & read sides identical):
//   Qs/Ks (row,k):   row*64  + ((k>>3) ^ (row&7))*8  + (k&7)
//   Vs    (d,key):   d*128   + ((key>>3) ^ (d&15))*8 + (key&7)
//   Ps    (q,key):   q*128   + ((key>>3) ^ (q&15))*8 + (key&7)
// ---------------------------------------------------------------------------
__global__ __launch_bounds__(256) void fused_attn_k(
    const ushort* __restrict__ qg, const ushort* __restrict__ kg,
    const ushort* __restrict__ vtg, float* __restrict__ attn,
    ushort* __restrict__ ctxb) {
  __shared__ ushort Qs[128 * 64];    // 16 KB
  __shared__ ushort Ks[128 * 64];    // 16 KB
  __shared__ ushort Vs[64 * 128];    // 16 KB  [d][key-slice]
  __shared__ ushort Ps[128 * 128];   // 32 KB

  const int tid = threadIdx.x;
  const int lane = tid & 63, wave = tid >> 6;
  const int bh = blockIdx.y;
  const int row0 = blockIdx.x * 128;
  const ushort* qp = qg + ((size_t)bh << 16) + (size_t)row0 * 64;
  const ushort* kp = kg + ((size_t)bh << 16);
  const ushort* vp = vtg + ((size_t)bh << 16);
  float* op = attn + (size_t)bh * SEQ * SEQ;

  const int srow = tid >> 3, sslot = tid & 7;   // Q/K staging (128x64)
  const int swz = sslot ^ (srow & 7);
  const int vrow = tid >> 4, vslot = tid & 15;  // V staging (64x128)
  const int fr = lane & 15, fk = lane >> 4;

  // stage Q once
#pragma unroll
  for (int j = 0; j < 4; ++j)
    *(u16x8*)(&Qs[(j * 32 + srow) * 64 + swz * 8]) =
        *(const u16x8*)(qp + (size_t)(j * 32 + srow) * 64 + sslot * 8);

  float m[2][4], l[2][4];
#pragma unroll
  for (int i = 0; i < 2; ++i)
#pragma unroll
    for (int e = 0; e < 4; ++e) { m[i][e] = -1e30f; l[i][e] = 0.f; }

  u16x8 rk[4];
#pragma unroll
  for (int j = 0; j < 4; ++j)
    rk[j] = *(const u16x8*)(kp + (size_t)(j * 32 + srow) * 64 + sslot * 8);

  // ---------------- pass 1: stats ----------------
  for (int kt = 0; kt < 8; ++kt) {
    __syncthreads();
#pragma unroll
    for (int j = 0; j < 4; ++j)
      *(u16x8*)(&Ks[(j * 32 + srow) * 64 + swz * 8]) = rk[j];
    __syncthreads();
    if (kt < 7) {
#pragma unroll
      for (int j = 0; j < 4; ++j)
        rk[j] = *(const u16x8*)(kp + (size_t)((kt + 1) * 128 + j * 32 + srow) * 64 + sslot * 8);
    }
    f32x4 s[2][8];
#pragma unroll
    for (int i = 0; i < 2; ++i)
#pragma unroll
      for (int j = 0; j < 8; ++j)
#pragma unroll
        for (int e = 0; e < 4; ++e) s[i][j][e] = 0.f;
#pragma unroll
    for (int kk = 0; kk < 2; ++kk) {
      bf16x8 af[2], bf[8];
#pragma unroll
      for (int i = 0; i < 2; ++i) {
        const int q = wave * 32 + i * 16 + fr;
        af[i] = *(const bf16x8*)(&Qs[q * 64 + ((kk * 4 + fk) ^ (q & 7)) * 8]);
      }
#pragma unroll
      for (int j = 0; j < 8; ++j) {
        const int ky = j * 16 + fr;
        bf[j] = *(const bf16x8*)(&Ks[ky * 64 + ((kk * 4 + fk) ^ (ky & 7)) * 8]);
      }
#pragma unroll
      for (int i = 0; i < 2; ++i)
#pragma unroll
        for (int j = 0; j < 8; ++j)
          s[i][j] = __builtin_amdgcn_mfma_f32_16x16x32_bf16(af[i], bf[j], s[i][j], 0, 0, 0);
    }
    // online stats (raw s; softmax scale 1/8 folded into exp args)
#pragma unroll
    for (int i = 0; i < 2; ++i)
#pragma unroll
      for (int e = 0; e < 4; ++e) {
        float tmax = s[i][0][e];
#pragma unroll
        for (int j = 1; j < 8; ++j) tmax = fmaxf(tmax, s[i][j][e]);
#pragma unroll
        for (int o = 8; o > 0; o >>= 1) tmax = fmaxf(tmax, __shfl_xor(tmax, o));
        const float nm = fmaxf(m[i][e], tmax);
        const float sc = __expf((m[i][e] - nm) * 0.125f);
        float ts = 0.f;
#pragma unroll
        for (int j = 0; j < 8; ++j) ts += __expf((s[i][j][e] - nm) * 0.125f);
#pragma unroll
        for (int o = 8; o > 0; o >>= 1) ts += __shfl_xor(ts, o);
        l[i][e] = l[i][e] * sc + ts;
        m[i][e] = nm;
      }
  }
#pragma unroll
  for (int i = 0; i < 2; ++i)
#pragma unroll
    for (int e = 0; e < 4; ++e) l[i][e] = 1.f / l[i][e];   // l := 1/sum

  // ---------------- pass 2: P write + PV ----------------
  u16x8 rv[4];
#pragma unroll
  for (int j = 0; j < 4; ++j) {
    rk[j] = *(const u16x8*)(kp + (size_t)(j * 32 + srow) * 64 + sslot * 8);
    rv[j] = *(const u16x8*)(vp + (size_t)(j * 16 + vrow) * 1024 + vslot * 8);
  }
  f32x4 o_[2][4];
#pragma unroll
  for (int i = 0; i < 2; ++i)
#pragma unroll
    for (int jd = 0; jd < 4; ++jd)
#pragma unroll
      for (int e = 0; e < 4; ++e) o_[i][jd][e] = 0.f;

  for (int kt = 0; kt < 8; ++kt) {
    __syncthreads();   // Ks/Vs/Ps free (prev PV done)
#pragma unroll
    for (int j = 0; j < 4; ++j) {
      *(u16x8*)(&Ks[(j * 32 + srow) * 64 + swz * 8]) = rk[j];
      const int vr = j * 16 + vrow;
      *(u16x8*)(&Vs[vr * 128 + (vslot ^ (vr & 15)) * 8]) = rv[j];
    }
    __syncthreads();
    if (kt < 7) {
#pragma unroll
      for (int j = 0; j < 4; ++j) {
        rk[j] = *(const u16x8*)(kp + (size_t)((kt + 1) * 128 + j * 32 + srow) * 64 + sslot * 8);
        rv[j] = *(const u16x8*)(vp + (size_t)(j * 16 + vrow) * 1024 + (kt + 1) * 128 + vslot * 8);
      }
    }
    f32x4 s[2][8];
#pragma unroll
    for (int i = 0; i < 2; ++i)
#pragma unroll
      for (int j = 0; j < 8; ++j)
#pragma unroll
        for (int e = 0; e < 4; ++e) s[i][j][e] = 0.f;
#pragma unroll
    for (int kk = 0; kk < 2; ++kk) {
      bf16x8 af[2], bf[8];
#pragma unroll
      for (int i = 0; i < 2; ++i) {
        const int q = wave * 32 + i * 16 + fr;
        af[i] = *(const bf16x8*)(&Qs[q * 64 + ((kk * 4 + fk) ^ (q & 7)) * 8]);
      }
#pragma unroll
      for (int j = 0; j < 8; ++j) {
        const int ky = j * 16 + fr;
        bf[j] = *(const bf16x8*)(&Ks[ky * 64 + ((kk * 4 + fk) ^ (ky & 7)) * 8]);
      }
#pragma unroll
      for (int i = 0; i < 2; ++i)
#pragma unroll
        for (int j = 0; j < 8; ++j)
          s[i][j] = __builtin_amdgcn_mfma_f32_16x16x32_bf16(af[i], bf[j], s[i][j], 0, 0, 0);
    }
    // P = exp((s-m)/8)*rl -> attn (f32, only slab write) + Ps (bf16)
#pragma unroll
    for (int i = 0; i < 2; ++i)
#pragma unroll
      for (int e = 0; e < 4; ++e) {
        const int qrow = wave * 32 + i * 16 + fk * 4 + e;   // qrow&15 == fk*4+e
        const int gq = row0 + qrow;
#pragma unroll
        for (int j = 0; j < 8; ++j) {
          const float p = __expf((s[i][j][e] - m[i][e]) * 0.125f) * l[i][e];
          const int kl = j * 16 + fr;
          op[(size_t)gq * SEQ + kt * 128 + kl] = p;
          Ps[qrow * 128 + ((kl >> 3) ^ (qrow & 15)) * 8 + (kl & 7)] = f2bf(p);
        }
      }
    __syncthreads();   // Ps/Vs ready
#pragma unroll
    for (int kk = 0; kk < 4; ++kk) {
      bf16x8 pa[2], vb[4];
#pragma unroll
      for (int i = 0; i < 2; ++i) {
        const int q = wave * 32 + i * 16 + fr;              // q&15 == fr
        pa[i] = *(const bf16x8*)(&Ps[q * 128 + ((kk * 4 + fk) ^ fr) * 8]);
      }
#pragma unroll
      for (int jd = 0; jd < 4; ++jd) {
        const int d = jd * 16 + fr;                         // d&15 == fr
        vb[jd] = *(const bf16x8*)(&Vs[d * 128 + ((kk * 4 + fk) ^ fr) * 8]);
      }
#pragma unroll
      for (int i = 0; i < 2; ++i)
#pragma unroll
        for (int jd = 0; jd < 4; ++jd)
          o_[i][jd] = __builtin_amdgcn_mfma_f32_16x16x32_bf16(pa[i], vb[jd], o_[i][jd], 0, 0, 0);
    }
  }

  // write ctx bf16 [M, HID]
  const int b_ = bh >> 4, h_ = bh & 15;
#pragma unroll
  for (int i = 0; i < 2; ++i)
#pragma unroll
    for (int e = 0; e < 4; ++e) {
      const int gq = row0 + wave * 32 + i * 16 + fk * 4 + e;
#pragma unroll
      for (int jd = 0; jd < 4; ++jd) {
        const int d = jd * 16 + fr;
        ctxb[(size_t)(b_ * SEQ + gq) * HID + h_ * HD + d] = f2bf(o_[i][jd][e]);
      }
    }
}

// ---------------------------------------------------------------------------
extern "C" void kernel_launch(void* const* d_in, const int* in_sizes, int n_in,
                              void* d_out, int out_size, void* d_ws, size_t ws_size,
                              hipStream_t stream) {
  const float* x  = (const float*)d_in[0];
  const float* Wq = (const float*)d_in[1];
  const float* bq = (const float*)d_in[2];
  const float* Wk = (const float*)d_in[3];
  const float* bk = (const float*)d_in[4];
  const float* Wv = (const float*)d_in[5];
  const float* bv = (const float*)d_in[6];
  const float* Wo = (const float*)d_in[7];
  const float* bo = (const float*)d_in[8];

  float* out  = (float*)d_out;                         // [8,1024,1024]
  float* attn = out + (size_t)MTOK * HID;              // [8,16,1024,1024] f32

  ushort* wsb = (ushort*)d_ws;
  ushort* xbf = wsb;                                   // [M,K]       16 MB
  ushort* wqb = xbf + (size_t)MTOK * HID;              // [N,K]        2 MB
  ushort* wkb = wqb + HID * HID;
  ushort* wvb = wkb + HID * HID;
  ushort* wob = wvb + HID * HID;
  ushort* qbf = wob + HID * HID;                       // [B,H,S,HD]  16 MB
  ushort* kbf = qbf + (size_t)MTOK * HID;              // [B,H,S,HD]  16 MB
  ushort* vtb = kbf + (size_t)MTOK * HID;              // [B,H,HD,S]  16 MB
  ushort* cxb = vtb + (size_t)MTOK * HID;              // [M,HID]     16 MB

  const dim3 blk(256);
  cvtbf_k<<<(MTOK * HID) / 2048, blk, 0, stream>>>(x, xbf);
  cvtbf_k<<<(HID * HID) / 2048, blk, 0, stream>>>(Wq, wqb);
  cvtbf_k<<<(HID * HID) / 2048, blk, 0, stream>>>(Wk, wkb);
  cvtbf_k<<<(HID * HID) / 2048, blk, 0, stream>>>(Wv, wvb);
  cvtbf_k<<<(HID * HID) / 2048, blk, 0, stream>>>(Wo, wob);

  const dim3 g1(HID / 128, MTOK / 128);                // (8, 64)
  gemm_bf16_k<1><<<g1, blk, 0, stream>>>(xbf, wqb, bq, nullptr, qbf, HID, HID);
  gemm_bf16_k<1><<<g1, blk, 0, stream>>>(xbf, wkb, bk, nullptr, kbf, HID, HID);
  gemm_bf16_k<2><<<g1, blk, 0, stream>>>(xbf, wvb, bv, nullptr, vtb, HID, HID);

  fused_attn_k<<<dim3(SEQ / 128, NB * NH), blk, 0, stream>>>(qbf, kbf, vtb, attn, cxb);

  gemm_bf16_k<0><<<g1, blk, 0, stream>>>(cxb, wob, bo, out, nullptr, HID, HID);
}